// Round 2
// baseline (264.474 us; speedup 1.0000x reference)
//
#include <hip/hip_runtime.h>
#include <hip/hip_cooperative_groups.h>
#include <math.h>

namespace cg = cooperative_groups;

#define L 16384
#define H 128
#define P 256
#define CL 32
#define NCH (L/CL)   // 512 chunks
#define GS 16        // chunks per group
#define NG (NCH/GS)  // 32 groups
#define KDIM 512     // out-GEMM K = [x2re | x2im]
#define NBU 512      // bu-GEMM N  = [BuRe | BuIm]

typedef __attribute__((ext_vector_type(8))) short short8;   // 8 bf16
typedef __attribute__((ext_vector_type(4))) float f32x4;

__device__ inline unsigned short f2bf(float f){          // fp32 -> bf16 RNE
  union { float f; unsigned u; } v; v.f = f;
  unsigned u = v.u;
  u += 0x7fffu + ((u >> 16) & 1u);
  return (unsigned short)(u >> 16);
}
__device__ inline float bf2f(unsigned short s){
  union { unsigned u; float f; } v; v.u = ((unsigned)s) << 16;
  return v.f;
}

struct Params { float M11,M12,M21,M22,s1,s2; };

__device__ inline Params get_params(const float* A_diag, const float* steps, int p){
  float A = A_diag[p]; A = A > 0.f ? A : 0.f;          // relu
  float dt = 1.f/(1.f + expf(-steps[p]));              // sigmoid
  float schur = 1.f/(1.f + dt*dt*A);
  Params q;
  q.M11 = 1.f - dt*dt*A*schur;
  q.M12 = -dt*A*schur;
  q.M21 = dt*schur;
  q.M22 = schur;
  q.s1 = q.M11*dt;
  q.s2 = q.M21*dt;
  return q;
}

// Single cooperative kernel. Block c owns chunk c for the whole lifetime:
// sBu stays in LDS across grid syncs (blocks are co-resident, never preempted).
__global__ __launch_bounds__(512, 4) void linoss_all(
    const float* __restrict__ in,      // (L,H) fp32
    const float* __restrict__ B,       // (P,H,2)
    const float* __restrict__ Cw,      // (H,P,2)
    const float* __restrict__ A_diag,  // (P,)
    const float* __restrict__ steps,   // (P,)
    const float* __restrict__ Dv,      // (H,)
    unsigned short* __restrict__ BWswz,// (H/8,512,8) bf16 MFMA-B layout for Bu GEMM
    unsigned short* __restrict__ Bswz, // (512/8,H,8) bf16 MFMA-B layout for out GEMM
    float* __restrict__ finals,        // 2 parts x NCH x P float2
    float* __restrict__ gfin,          // 2 parts x NG  x P float2
    float* __restrict__ out)           // (L,H) fp32
{
  __shared__ unsigned short sX[CL][NBU+8];   // Bu (bf16), overwritten in place by x2
  cg::grid_group grid = cg::this_grid();
  const int c   = blockIdx.x;
  const int tid = threadIdx.x;

  // ---------------- Phase A: weight swizzles (grid-stride over 131072 elems) ----
  {
    int gidx = c*512 + tid;
    if (gidx < H*NBU){                         // BW swizzle (k=h 0..127, n 0..511)
      int k = gidx >> 9, n = gidx & 511;
      int p = n & 255, c2 = n >> 8;
      float v = B[((size_t)p*H + k)*2 + c2];
      BWswz[((size_t)(k>>3)*NBU + n)*8 + (k&7)] = f2bf(v);
    } else if (gidx < 2*H*NBU){                // C swizzle (k 0..511, n=h 0..127)
      int g2 = gidx - H*NBU;
      int k = g2 >> 7, n = g2 & 127;
      float v = (k < P) ? Cw[((size_t)n*P + k)*2]
                        : -Cw[((size_t)n*P + (k-P))*2 + 1];
      Bswz[((size_t)(k>>3)*H + n)*8 + (k&7)] = f2bf(v);
    }
  }
  grid.sync();

  // ---------------- Phase B: chunk Bu via MFMA (fp32 load, bf16 in-reg) --------
  {
    int lane = tid & 63, w = tid >> 6;
    int ml = lane & 15, quad = lane >> 4;
    int mt = w & 1, ng = w >> 1;
    int lm0 = mt*16;
    const float* aptr = in + (size_t)(c*CL + lm0 + ml)*H + quad*8;
    short8 av[4];
    #pragma unroll
    for (int ks=0; ks<4; ks++){
      float4 f0 = *(const float4*)(aptr + ks*32);
      float4 f1 = *(const float4*)(aptr + ks*32 + 4);
      union { short8 s; unsigned short u[8]; } o;
      o.u[0]=f2bf(f0.x); o.u[1]=f2bf(f0.y); o.u[2]=f2bf(f0.z); o.u[3]=f2bf(f0.w);
      o.u[4]=f2bf(f1.x); o.u[5]=f2bf(f1.y); o.u[6]=f2bf(f1.z); o.u[7]=f2bf(f1.w);
      av[ks] = o.s;
    }
    f32x4 acc[8];
    #pragma unroll
    for (int t=0;t<8;t++) acc[t] = (f32x4){0.f,0.f,0.f,0.f};
    #pragma unroll
    for (int ks=0; ks<4; ks++){
      #pragma unroll
      for (int t=0;t<8;t++){
        int n0 = (ng*8 + t)*16;
        short8 bv = *(const short8*)(BWswz + ((size_t)(ks*4+quad)*NBU + n0 + ml)*8);
        acc[t] = __builtin_amdgcn_mfma_f32_16x16x32_bf16(av[ks], bv, acc[t], 0, 0, 0);
      }
    }
    #pragma unroll
    for (int t=0;t<8;t++){
      int n = (ng*8+t)*16 + ml;
      #pragma unroll
      for (int r=0;r<4;r++)
        sX[lm0 + quad*4 + r][n] = f2bf(acc[t][r]);
    }
  }
  __syncthreads();

  // ---------------- Phase B2: local scan over chunk -> finals ------------------
  const int p = tid & 255, part = tid >> 8;
  Params q = get_params(A_diag, steps, p);
  // T = M^32 (needed by phases C and D)
  float Ta=q.M11, Tb=q.M12, Tc=q.M21, Td=q.M22;
  #pragma unroll
  for (int s=0;s<5;s++){
    float na=Ta*Ta+Tb*Tc, nb=Ta*Tb+Tb*Td, nc=Tc*Ta+Td*Tc, nd=Tc*Tb+Td*Td;
    Ta=na;Tb=nb;Tc=nc;Td=nd;
  }
  {
    float x1=0.f, x2=0.f;
    #pragma unroll
    for (int i=0;i<CL;i++){
      float u = bf2f(sX[i][part*256 + p]);
      float n1 = q.M11*x1 + q.M12*x2 + q.s1*u;
      float n2 = q.M21*x1 + q.M22*x2 + q.s2*u;
      x1 = n1; x2 = n2;
    }
    ((float2*)finals)[(size_t)(part*NCH + c)*P + p] = make_float2(x1,x2);
  }
  grid.sync();

  // ---------------- Phase C: group totals (blocks 0..31 only) ------------------
  if (c < NG){
    const float2* f2p = (const float2*)finals;
    float x1=0.f, x2=0.f;
    #pragma unroll
    for (int i=0;i<GS;i++){
      float2 f = f2p[(size_t)(part*NCH + c*GS + i)*P + p];
      float n1 = Ta*x1 + Tb*x2 + f.x;
      float n2 = Tc*x1 + Td*x2 + f.y;
      x1=n1; x2=n2;
    }
    ((float2*)gfin)[(size_t)(part*NG + c)*P + p] = make_float2(x1,x2);
  }
  grid.sync();

  // ---------------- Phase D: carry-in, in-LDS scan, out GEMM -------------------
  {
    int g = c >> 4, iw = c & (GS-1);
    // S = T^iw (iw wave-uniform)
    float sa=1.f, sb=0.f, sc=0.f, sd=1.f;
    {
      float wa=Ta, wb=Tb, wc=Tc, wd=Td;
      #pragma unroll
      for (int bit=0; bit<4; bit++){
        if ((iw>>bit)&1){
          float na = wa*sa + wb*sc, nb = wa*sb + wb*sd;
          float nc = wc*sa + wd*sc, nd = wc*sb + wd*sd;
          sa=na; sb=nb; sc=nc; sd=nd;
        }
        float qa = wa*wa + wb*wc, qb = wa*wb + wb*wd;
        float qc = wc*wa + wd*wc, qd = wc*wb + wd*wd;
        wa=qa; wb=qb; wc=qc; wd=qd;
      }
    }
    // T_G = M^512 = T^16 (4 more squarings)
    float ga=Ta, gb=Tb, gc=Tc, gd=Td;
    #pragma unroll
    for (int s=0;s<4;s++){
      float na=ga*ga+gb*gc, nb=ga*gb+gb*gd, nc=gc*ga+gd*gc, nd=gc*gb+gd*gd;
      ga=na;gb=nb;gc=nc;gd=nd;
    }
    // Y_g = sequential combine over gfin[0..g-1] (g wave-uniform, <=31 iters, L2-hit)
    float y1=0.f, y2=0.f;
    const float2* Z2 = (const float2*)gfin;
    for (int j=0; j<g; j++){
      float2 z = Z2[(size_t)(part*NG + j)*P + p];
      float n1 = ga*y1 + gb*y2 + z.x;
      float n2 = gc*y1 + gd*y2 + z.y;
      y1=n1; y2=n2;
    }
    // zc = exclusive in-group prefix of chunk finals (iw wave-uniform, <=15 iters)
    float z1=0.f, z2v=0.f;
    {
      const float2* f2p = (const float2*)finals;
      for (int j=0; j<iw; j++){
        float2 f = f2p[(size_t)(part*NCH + g*GS + j)*P + p];
        float n1 = Ta*z1 + Tb*z2v + f.x;
        float n2 = Tc*z1 + Td*z2v + f.y;
        z1=n1; z2v=n2;
      }
    }
    float x1 = sa*y1 + sb*y2 + z1;
    float x2 = sc*y1 + sd*y2 + z2v;
    #pragma unroll
    for (int i=0;i<CL;i++){
      float u = bf2f(sX[i][part*256 + p]);
      float n1 = q.M11*x1 + q.M12*x2 + q.s1*u;
      float n2 = q.M21*x1 + q.M22*x2 + q.s2*u;
      x1 = n1; x2 = n2;
      sX[i][part*256 + p] = f2bf(x2);
    }
  }
  __syncthreads();

  // out GEMM: 32 rows x 128 h, A from LDS, 2 n-tiles per wave
  {
    int lane = tid & 63, w = tid >> 6;
    int ml = lane & 15, quad = lane >> 4;
    int mt = w & 1;
    int ntb = (w >> 1) * 2;
    f32x4 acc[2];
    acc[0] = (f32x4){0.f,0.f,0.f,0.f};
    acc[1] = (f32x4){0.f,0.f,0.f,0.f};
    for (int ks=0; ks<KDIM/32; ks++){
      short8 av = *(const short8*)&sX[mt*16 + ml][ks*32 + quad*8];
      #pragma unroll
      for (int j=0;j<2;j++){
        short8 bv = *(const short8*)(Bswz + ((size_t)(ks*4+quad)*H + (ntb+j)*16 + ml)*8);
        acc[j] = __builtin_amdgcn_mfma_f32_16x16x32_bf16(av, bv, acc[j], 0, 0, 0);
      }
    }
    #pragma unroll
    for (int j=0;j<2;j++){
      int h = (ntb+j)*16 + ml;
      float dv = Dv[h];
      #pragma unroll
      for (int r=0;r<4;r++){
        int l = c*CL + mt*16 + quad*4 + r;
        out[(size_t)l*H + h] = acc[j][r] + in[(size_t)l*H + h]*dv;
      }
    }
  }
}

extern "C" void kernel_launch(void* const* d_in, const int* in_sizes, int n_in,
                              void* d_out, int out_size, void* d_ws, size_t ws_size,
                              hipStream_t stream) {
  const float* in     = (const float*)d_in[0];   // (L,H)
  const float* A_diag = (const float*)d_in[1];   // (P,)
  const float* B      = (const float*)d_in[2];   // (P,H,2)
  const float* Cw     = (const float*)d_in[3];   // (H,P,2)
  const float* Dv     = (const float*)d_in[4];   // (H,)
  const float* steps  = (const float*)d_in[5];   // (P,)
  float* out = (float*)d_out;

  unsigned short* BWswz = (unsigned short*)d_ws;             // 128*512 bf16 (128KB)
  unsigned short* Bswz  = BWswz + (size_t)H*NBU;             // 512*128 bf16 (128KB)
  float* finals = (float*)(Bswz + (size_t)KDIM*H);           // 2*NCH*P*2 fp32 (2MB)
  float* gfin   = finals + (size_t)2*NCH*P*2;                // 2*NG*P*2 fp32 (128KB)

  void* args[] = { (void*)&in, (void*)&B, (void*)&Cw, (void*)&A_diag, (void*)&steps,
                   (void*)&Dv, (void*)&BWswz, (void*)&Bswz, (void*)&finals,
                   (void*)&gfin, (void*)&out };
  hipLaunchCooperativeKernel((const void*)linoss_all, dim3(NCH), dim3(512),
                             args, 0, stream);
}

// Round 3
// 138.298 us; speedup vs baseline: 1.9123x; 1.9123x over previous
//
#include <hip/hip_runtime.h>
#include <math.h>

#define L 16384
#define H 128
#define P 256
#define CL 32
#define NCH (L/CL)   // 512 chunks
#define GS 16        // chunks per group
#define NG (NCH/GS)  // 32 groups
#define KDIM 512     // out-GEMM K = [x2re | x2im]
#define NBU 512      // bu-GEMM N  = [BuRe | BuIm]

typedef __attribute__((ext_vector_type(8))) short short8;   // 8 bf16
typedef __attribute__((ext_vector_type(4))) float f32x4;

__device__ inline unsigned short f2bf(float f){          // fp32 -> bf16 RNE
  union { float f; unsigned u; } v; v.f = f;
  unsigned u = v.u;
  u += 0x7fffu + ((u >> 16) & 1u);
  return (unsigned short)(u >> 16);
}
__device__ inline float bf2f(unsigned short s){
  union { unsigned u; float f; } v; v.u = ((unsigned)s) << 16;
  return v.f;
}

struct Params { float M11,M12,M21,M22,s1,s2; };

__device__ inline Params get_params(const float* A_diag, const float* steps, int p){
  float A = A_diag[p]; A = A > 0.f ? A : 0.f;          // relu
  float dt = 1.f/(1.f + expf(-steps[p]));              // sigmoid
  float schur = 1.f/(1.f + dt*dt*A);
  Params q;
  q.M11 = 1.f - dt*dt*A*schur;
  q.M12 = -dt*A*schur;
  q.M21 = dt*schur;
  q.M22 = schur;
  q.s1 = q.M11*dt;
  q.s2 = q.M21*dt;
  return q;
}

// Spin on a device-scope flag; relaxed spin + final acquire (invalidates L1/L2).
__device__ inline void spin_flag(unsigned* f){
  while (__hip_atomic_load(f, __ATOMIC_RELAXED, __HIP_MEMORY_SCOPE_AGENT) == 0u)
    __builtin_amdgcn_s_sleep(2);
  (void)__hip_atomic_load(f, __ATOMIC_ACQUIRE, __HIP_MEMORY_SCOPE_AGENT);
}

// ---- K0: weight swizzles + flag clear (256 blocks x 512 = 131072 threads) ----
__global__ __launch_bounds__(512) void prep_w(const float* __restrict__ B,
                                              const float* __restrict__ Cw,
                                              unsigned short* __restrict__ BWswz,
                                              unsigned short* __restrict__ Bswz,
                                              unsigned* __restrict__ flags){
  int gidx = blockIdx.x*512 + threadIdx.x;
  if (gidx < NCH + NG) flags[gidx] = 0u;       // 544 flags
  if (gidx < H*NBU){                           // BW swizzle (k=h 0..127, n 0..511)
    int k = gidx >> 9, n = gidx & 511;
    int p = n & 255, c2 = n >> 8;
    float v = B[((size_t)p*H + k)*2 + c2];
    BWswz[((size_t)(k>>3)*NBU + n)*8 + (k&7)] = f2bf(v);
  } else {                                     // C swizzle (k 0..511, n=h 0..127)
    int g2 = gidx - H*NBU;
    int k = g2 >> 7, n = g2 & 127;
    float v = (k < P) ? Cw[((size_t)n*P + k)*2]
                      : -Cw[((size_t)n*P + (k-P))*2 + 1];
    Bswz[((size_t)(k>>3)*H + n)*8 + (k&7)] = f2bf(v);
  }
}

// ---- K1: everything else, one block per chunk, decoupled-lookback sync ------
// All 512 blocks are co-resident (2 blocks/CU at 33.3KB LDS, <=128 VGPR) so
// flag spin-waits cannot deadlock (verified by successful coop launch @ R2).
__global__ __launch_bounds__(512, 4) void linoss_fused(
    const float* __restrict__ in,      // (L,H) fp32
    const float* __restrict__ A_diag,  // (P,)
    const float* __restrict__ steps,   // (P,)
    const float* __restrict__ Dv,      // (H,)
    const unsigned short* __restrict__ BWswz,
    const unsigned short* __restrict__ Bswz,
    float* __restrict__ finals,        // 2 parts x NCH x P float2
    float* __restrict__ gfin,          // 2 parts x NG  x P float2
    unsigned* __restrict__ flag1,      // [NCH]
    unsigned* __restrict__ flag2,      // [NG]
    float* __restrict__ out)           // (L,H) fp32
{
  __shared__ unsigned short sX[CL][NBU+8];   // Bu (bf16), overwritten in place by x2
  const int c   = blockIdx.x;
  const int tid = threadIdx.x;

  // ---------------- Phase B: chunk Bu via MFMA (fp32 load, bf16 in-reg) --------
  {
    int lane = tid & 63, w = tid >> 6;
    int ml = lane & 15, quad = lane >> 4;
    int mt = w & 1, ng = w >> 1;
    int lm0 = mt*16;
    const float* aptr = in + (size_t)(c*CL + lm0 + ml)*H + quad*8;
    short8 av[4];
    #pragma unroll
    for (int ks=0; ks<4; ks++){
      float4 f0 = *(const float4*)(aptr + ks*32);
      float4 f1 = *(const float4*)(aptr + ks*32 + 4);
      union { short8 s; unsigned short u[8]; } o;
      o.u[0]=f2bf(f0.x); o.u[1]=f2bf(f0.y); o.u[2]=f2bf(f0.z); o.u[3]=f2bf(f0.w);
      o.u[4]=f2bf(f1.x); o.u[5]=f2bf(f1.y); o.u[6]=f2bf(f1.z); o.u[7]=f2bf(f1.w);
      av[ks] = o.s;
    }
    f32x4 acc[8];
    #pragma unroll
    for (int t=0;t<8;t++) acc[t] = (f32x4){0.f,0.f,0.f,0.f};
    #pragma unroll
    for (int ks=0; ks<4; ks++){
      #pragma unroll
      for (int t=0;t<8;t++){
        int n0 = (ng*8 + t)*16;
        short8 bv = *(const short8*)(BWswz + ((size_t)(ks*4+quad)*NBU + n0 + ml)*8);
        acc[t] = __builtin_amdgcn_mfma_f32_16x16x32_bf16(av[ks], bv, acc[t], 0, 0, 0);
      }
    }
    #pragma unroll
    for (int t=0;t<8;t++){
      int n = (ng*8+t)*16 + ml;
      #pragma unroll
      for (int r=0;r<4;r++)
        sX[lm0 + quad*4 + r][n] = f2bf(acc[t][r]);
    }
  }
  __syncthreads();

  // ---------------- Phase B2: local scan over chunk -> publish finals ----------
  const int p = tid & 255, part = tid >> 8;
  Params q = get_params(A_diag, steps, p);
  float Ta=q.M11, Tb=q.M12, Tc=q.M21, Td=q.M22;     // T = M^32
  #pragma unroll
  for (int s=0;s<5;s++){
    float na=Ta*Ta+Tb*Tc, nb=Ta*Tb+Tb*Td, nc=Tc*Ta+Td*Tc, nd=Tc*Tb+Td*Td;
    Ta=na;Tb=nb;Tc=nc;Td=nd;
  }
  {
    float x1=0.f, x2=0.f;
    #pragma unroll
    for (int i=0;i<CL;i++){
      float u = bf2f(sX[i][part*256 + p]);
      float n1 = q.M11*x1 + q.M12*x2 + q.s1*u;
      float n2 = q.M21*x1 + q.M22*x2 + q.s2*u;
      x1 = n1; x2 = n2;
    }
    ((float2*)finals)[(size_t)(part*NCH + c)*P + p] = make_float2(x1,x2);
  }
  __syncthreads();                                   // all finals stores drained (vmcnt 0)
  if (tid == 0){
    __threadfence();                                 // push this XCD's L2 to coherence point
    __hip_atomic_store(&flag1[c], 1u, __ATOMIC_RELEASE, __HIP_MEMORY_SCOPE_AGENT);
  }

  const int g = c >> 4, iw = c & (GS-1);

  // ---------------- Phase C (group producer = last chunk of group) -------------
  if (iw == GS-1){
    if (tid < GS-1) spin_flag(&flag1[g*GS + tid]);   // wait for 15 group-mates
    __syncthreads();
    const float2* f2p = (const float2*)finals;
    float x1=0.f, x2=0.f;
    #pragma unroll
    for (int i=0;i<GS;i++){
      float2 f = f2p[(size_t)(part*NCH + g*GS + i)*P + p];
      float n1 = Ta*x1 + Tb*x2 + f.x;
      float n2 = Tc*x1 + Td*x2 + f.y;
      x1=n1; x2=n2;
    }
    ((float2*)gfin)[(size_t)(part*NG + g)*P + p] = make_float2(x1,x2);
    __syncthreads();
    if (tid == 0){
      __threadfence();
      __hip_atomic_store(&flag2[g], 1u, __ATOMIC_RELEASE, __HIP_MEMORY_SCOPE_AGENT);
    }
  }

  // ---------------- Consumer wait: <=31 group flags + <=15 chunk flags ---------
  if (tid < g)                       spin_flag(&flag2[tid]);
  else if (tid >= 64 && tid < 64+iw) spin_flag(&flag1[g*GS + (tid-64)]);
  __syncthreads();

  // ---------------- Phase D: carry-in, in-LDS scan -----------------------------
  {
    // S = T^iw (iw wave-uniform)
    float sa=1.f, sb=0.f, sc=0.f, sd=1.f;
    {
      float wa=Ta, wb=Tb, wc=Tc, wd=Td;
      #pragma unroll
      for (int bit=0; bit<4; bit++){
        if ((iw>>bit)&1){
          float na = wa*sa + wb*sc, nb = wa*sb + wb*sd;
          float nc = wc*sa + wd*sc, nd = wc*sb + wd*sd;
          sa=na; sb=nb; sc=nc; sd=nd;
        }
        float qa = wa*wa + wb*wc, qb = wa*wb + wb*wd;
        float qc = wc*wa + wd*wc, qd = wc*wb + wd*wd;
        wa=qa; wb=qb; wc=qc; wd=qd;
      }
    }
    // T_G = T^16
    float ga=Ta, gb=Tb, gc=Tc, gd=Td;
    #pragma unroll
    for (int s=0;s<4;s++){
      float na=ga*ga+gb*gc, nb=ga*gb+gb*gd, nc=gc*ga+gd*gc, nd=gc*gb+gd*gd;
      ga=na;gb=nb;gc=nc;gd=nd;
    }
    // Y_g over gfin[0..g-1]
    float y1=0.f, y2=0.f;
    const float2* Z2 = (const float2*)gfin;
    for (int j=0; j<g; j++){
      float2 z = Z2[(size_t)(part*NG + j)*P + p];
      float n1 = ga*y1 + gb*y2 + z.x;
      float n2 = gc*y1 + gd*y2 + z.y;
      y1=n1; y2=n2;
    }
    // zc = exclusive in-group prefix from finals (<=15 iters)
    float z1=0.f, z2v=0.f;
    {
      const float2* f2p = (const float2*)finals;
      for (int j=0; j<iw; j++){
        float2 f = f2p[(size_t)(part*NCH + g*GS + j)*P + p];
        float n1 = Ta*z1 + Tb*z2v + f.x;
        float n2 = Tc*z1 + Td*z2v + f.y;
        z1=n1; z2v=n2;
      }
    }
    float x1 = sa*y1 + sb*y2 + z1;
    float x2 = sc*y1 + sd*y2 + z2v;
    #pragma unroll
    for (int i=0;i<CL;i++){
      float u = bf2f(sX[i][part*256 + p]);
      float n1 = q.M11*x1 + q.M12*x2 + q.s1*u;
      float n2 = q.M21*x1 + q.M22*x2 + q.s2*u;
      x1 = n1; x2 = n2;
      sX[i][part*256 + p] = f2bf(x2);
    }
  }
  __syncthreads();

  // ---------------- out GEMM: 32 rows x 128 h ----------------------------------
  {
    int lane = tid & 63, w = tid >> 6;
    int ml = lane & 15, quad = lane >> 4;
    int mt = w & 1;
    int ntb = (w >> 1) * 2;
    f32x4 acc[2];
    acc[0] = (f32x4){0.f,0.f,0.f,0.f};
    acc[1] = (f32x4){0.f,0.f,0.f,0.f};
    for (int ks=0; ks<KDIM/32; ks++){
      short8 av = *(const short8*)&sX[mt*16 + ml][ks*32 + quad*8];
      #pragma unroll
      for (int j=0;j<2;j++){
        short8 bv = *(const short8*)(Bswz + ((size_t)(ks*4+quad)*H + (ntb+j)*16 + ml)*8);
        acc[j] = __builtin_amdgcn_mfma_f32_16x16x32_bf16(av, bv, acc[j], 0, 0, 0);
      }
    }
    #pragma unroll
    for (int j=0;j<2;j++){
      int h = (ntb+j)*16 + ml;
      float dv = Dv[h];
      #pragma unroll
      for (int r=0;r<4;r++){
        int l = c*CL + mt*16 + quad*4 + r;
        out[(size_t)l*H + h] = acc[j][r] + in[(size_t)l*H + h]*dv;
      }
    }
  }
}

extern "C" void kernel_launch(void* const* d_in, const int* in_sizes, int n_in,
                              void* d_out, int out_size, void* d_ws, size_t ws_size,
                              hipStream_t stream) {
  const float* in     = (const float*)d_in[0];   // (L,H)
  const float* A_diag = (const float*)d_in[1];   // (P,)
  const float* B      = (const float*)d_in[2];   // (P,H,2)
  const float* Cw     = (const float*)d_in[3];   // (H,P,2)
  const float* Dv     = (const float*)d_in[4];   // (H,)
  const float* steps  = (const float*)d_in[5];   // (P,)
  float* out = (float*)d_out;

  unsigned short* BWswz = (unsigned short*)d_ws;             // 128*512 bf16 (128KB)
  unsigned short* Bswz  = BWswz + (size_t)H*NBU;             // 512*128 bf16 (128KB)
  float* finals = (float*)(Bswz + (size_t)KDIM*H);           // 2*NCH*P*2 fp32 (2MB)
  float* gfin   = finals + (size_t)2*NCH*P*2;                // 2*NG*P*2 fp32 (128KB)
  unsigned* flags = (unsigned*)(gfin + (size_t)2*NG*P*2);    // 544 flags
  unsigned* flag1 = flags;                                   // [512]
  unsigned* flag2 = flags + NCH;                             // [32]

  prep_w<<<256, 512, 0, stream>>>(B, Cw, BWswz, Bswz, flags);
  linoss_fused<<<NCH, 512, 0, stream>>>(in, A_diag, steps, Dv, BWswz, Bswz,
                                        finals, gfin, flag1, flag2, out);
}

// Round 4
// 98.222 us; speedup vs baseline: 2.6926x; 1.4080x over previous
//
#include <hip/hip_runtime.h>
#include <math.h>

#define L 16384
#define H 128
#define P 256
#define CL 32
#define NCH (L/CL)   // 512 chunks
#define GS 16        // chunks per group
#define NG (NCH/GS)  // 32 groups
#define KDIM 512     // out-GEMM K = [x2re | x2im]
#define NBU 512      // bu-GEMM N  = [BuRe | BuIm]

#define SENT 0xFFC0DEADFFC0DEADULL   // NaN-payload sentinel (unproducible by finite math)
#define SENT_WORDS (2*NCH*P + 2*NG*P)   // finals + gfin = 278528 ulongs

typedef __attribute__((ext_vector_type(8))) short short8;   // 8 bf16
typedef __attribute__((ext_vector_type(4))) float f32x4;

__device__ inline unsigned short f2bf(float f){          // fp32 -> bf16 RNE
  union { float f; unsigned u; } v; v.f = f;
  unsigned u = v.u;
  u += 0x7fffu + ((u >> 16) & 1u);
  return (unsigned short)(u >> 16);
}
__device__ inline float bf2f(unsigned short s){
  union { unsigned u; float f; } v; v.u = ((unsigned)s) << 16;
  return v.f;
}

struct Params { float M11,M12,M21,M22,s1,s2; };

__device__ inline Params get_params(const float* A_diag, const float* steps, int p){
  float A = A_diag[p]; A = A > 0.f ? A : 0.f;          // relu
  float dt = 1.f/(1.f + expf(-steps[p]));              // sigmoid
  float schur = 1.f/(1.f + dt*dt*A);
  Params q;
  q.M11 = 1.f - dt*dt*A*schur;
  q.M12 = -dt*A*schur;
  q.M21 = dt*schur;
  q.M22 = schur;
  q.s1 = q.M11*dt;
  q.s2 = q.M21*dt;
  return q;
}

// Relaxed agent-scope atomics: no buffer_inv / buffer_wbl2 cache maintenance.
__device__ inline unsigned long long aload(const unsigned long long* p){
  return __hip_atomic_load((unsigned long long*)p, __ATOMIC_RELAXED,
                           __HIP_MEMORY_SCOPE_AGENT);
}
__device__ inline void apub(unsigned long long* p, unsigned long long v){
  // exchange (RMW) is performed at the coherence point (MALL) — globally
  // visible without any release fence; returned old value discarded.
  (void)__hip_atomic_exchange(p, v, __ATOMIC_RELAXED, __HIP_MEMORY_SCOPE_AGENT);
}

// ---- K0: weight swizzles + sentinel fill (544 blocks x 512) -----------------
__global__ __launch_bounds__(512) void prep_w(const float* __restrict__ B,
                                              const float* __restrict__ Cw,
                                              unsigned short* __restrict__ BWswz,
                                              unsigned short* __restrict__ Bswz,
                                              unsigned long long* __restrict__ sent){
  int gidx = blockIdx.x*512 + threadIdx.x;
  sent[gidx] = SENT;                           // covers finals+gfin exactly (278528)
  if (gidx < H*NBU){                           // BW swizzle (k=h 0..127, n 0..511)
    int k = gidx >> 9, n = gidx & 511;
    int p = n & 255, c2 = n >> 8;
    float v = B[((size_t)p*H + k)*2 + c2];
    BWswz[((size_t)(k>>3)*NBU + n)*8 + (k&7)] = f2bf(v);
  } else if (gidx < 2*H*NBU){                  // C swizzle (k 0..511, n=h 0..127)
    int g2 = gidx - H*NBU;
    int k = g2 >> 7, n = g2 & 127;
    float v = (k < P) ? Cw[((size_t)n*P + k)*2]
                      : -Cw[((size_t)n*P + (k-P))*2 + 1];
    Bswz[((size_t)(k>>3)*H + n)*8 + (k&7)] = f2bf(v);
  }
}

// ---- K1: fully fused, fence-free data-as-flag sync --------------------------
// All 512 blocks co-resident (2 blocks/CU: 33.3KB LDS, <=128 VGPR via
// launch_bounds(512,4)) -> spin-waits cannot deadlock (proven R2/R3).
__global__ __launch_bounds__(512, 4) void linoss_fused(
    const float* __restrict__ in,      // (L,H) fp32
    const float* __restrict__ A_diag,  // (P,)
    const float* __restrict__ steps,   // (P,)
    const float* __restrict__ Dv,      // (H,)
    const unsigned short* __restrict__ BWswz,
    const unsigned short* __restrict__ Bswz,
    unsigned long long* __restrict__ finals, // [2][NCH][P] float2-as-u64
    unsigned long long* __restrict__ gfin,   // [2][NG][P]  float2-as-u64
    float* __restrict__ out)           // (L,H) fp32
{
  __shared__ unsigned short sX[CL][NBU+8];   // Bu (bf16), overwritten in place by x2
  const int c   = blockIdx.x;
  const int tid = threadIdx.x;

  // ---------------- Phase B: chunk Bu via MFMA (fp32 load, bf16 in-reg) --------
  {
    int lane = tid & 63, w = tid >> 6;
    int ml = lane & 15, quad = lane >> 4;
    int mt = w & 1, ng = w >> 1;
    int lm0 = mt*16;
    const float* aptr = in + (size_t)(c*CL + lm0 + ml)*H + quad*8;
    short8 av[4];
    #pragma unroll
    for (int ks=0; ks<4; ks++){
      float4 f0 = *(const float4*)(aptr + ks*32);
      float4 f1 = *(const float4*)(aptr + ks*32 + 4);
      union { short8 s; unsigned short u[8]; } o;
      o.u[0]=f2bf(f0.x); o.u[1]=f2bf(f0.y); o.u[2]=f2bf(f0.z); o.u[3]=f2bf(f0.w);
      o.u[4]=f2bf(f1.x); o.u[5]=f2bf(f1.y); o.u[6]=f2bf(f1.z); o.u[7]=f2bf(f1.w);
      av[ks] = o.s;
    }
    f32x4 acc[8];
    #pragma unroll
    for (int t=0;t<8;t++) acc[t] = (f32x4){0.f,0.f,0.f,0.f};
    #pragma unroll
    for (int ks=0; ks<4; ks++){
      #pragma unroll
      for (int t=0;t<8;t++){
        int n0 = (ng*8 + t)*16;
        short8 bv = *(const short8*)(BWswz + ((size_t)(ks*4+quad)*NBU + n0 + ml)*8);
        acc[t] = __builtin_amdgcn_mfma_f32_16x16x32_bf16(av[ks], bv, acc[t], 0, 0, 0);
      }
    }
    #pragma unroll
    for (int t=0;t<8;t++){
      int n = (ng*8+t)*16 + ml;
      #pragma unroll
      for (int r=0;r<4;r++)
        sX[lm0 + quad*4 + r][n] = f2bf(acc[t][r]);
    }
  }
  __syncthreads();

  // ---------------- Phase B2: local chunk scan -> publish own final ------------
  const int p = tid & 255, part = tid >> 8;
  Params q = get_params(A_diag, steps, p);
  float Ta=q.M11, Tb=q.M12, Tc=q.M21, Td=q.M22;     // T = M^32
  #pragma unroll
  for (int s=0;s<5;s++){
    float na=Ta*Ta+Tb*Tc, nb=Ta*Tb+Tb*Td, nc=Tc*Ta+Td*Tc, nd=Tc*Tb+Td*Td;
    Ta=na;Tb=nb;Tc=nc;Td=nd;
  }
  float fx1=0.f, fx2=0.f;                            // this chunk's final
  {
    #pragma unroll
    for (int i=0;i<CL;i++){
      float u = bf2f(sX[i][part*256 + p]);
      float n1 = q.M11*fx1 + q.M12*fx2 + q.s1*u;
      float n2 = q.M21*fx1 + q.M22*fx2 + q.s2*u;
      fx1 = n1; fx2 = n2;
    }
    union { unsigned long long u; float2 f; } w; w.f = make_float2(fx1,fx2);
    apub(&finals[(size_t)(part*NCH + c)*P + p], w.u);
  }

  const int g = c >> 4, iw = c & (GS-1);
  const unsigned long long* Fp = finals + (size_t)part*NCH*P + (size_t)g*GS*P + p;

  // ---------------- Phase C: group producer (iw==15) ---------------------------
  float z1=0.f, z2v=0.f;            // exclusive in-group mate prefix (chain T)
  bool have_z = false;
  if (iw == GS-1){
    unsigned long long v[GS-1];
    #pragma unroll
    for (int j=0;j<GS-1;j++) v[j] = aload(Fp + (size_t)j*P);
    #pragma unroll
    for (int j=0;j<GS-1;j++){
      while (v[j]==SENT){ __builtin_amdgcn_s_sleep(2); v[j] = aload(Fp + (size_t)j*P); }
    }
    #pragma unroll
    for (int j=0;j<GS-1;j++){
      union { unsigned long long u; float2 f; } w; w.u = v[j];
      float n1 = Ta*z1 + Tb*z2v + w.f.x;
      float n2 = Tc*z1 + Td*z2v + w.f.y;
      z1=n1; z2v=n2;
    }
    have_z = true;
    // group total = combine(z, own final); publish
    float t1 = Ta*z1 + Tb*z2v + fx1;
    float t2 = Tc*z1 + Td*z2v + fx2;
    union { unsigned long long u; float2 f; } w; w.f = make_float2(t1,t2);
    apub(&gfin[(size_t)(part*NG + g)*P + p], w.u);
  }

  // ---------------- Phase D: carries ------------------------------------------
  {
    // S = T^iw (iw wave-uniform)
    float sa=1.f, sb=0.f, sc=0.f, sd=1.f;
    {
      float wa=Ta, wb=Tb, wc=Tc, wd=Td;
      #pragma unroll
      for (int bit=0; bit<4; bit++){
        if ((iw>>bit)&1){
          float na = wa*sa + wb*sc, nb = wa*sb + wb*sd;
          float nc = wc*sa + wd*sc, nd = wc*sb + wd*sd;
          sa=na; sb=nb; sc=nc; sd=nd;
        }
        float qa = wa*wa + wb*wc, qb = wa*wb + wb*wd;
        float qc = wc*wa + wd*wc, qd = wc*wb + wd*wd;
        wa=qa; wb=qb; wc=qc; wd=qd;
      }
    }
    // T_G = T^16
    float ga=Ta, gb=Tb, gc=Tc, gd=Td;
    #pragma unroll
    for (int s=0;s<4;s++){
      float na=ga*ga+gb*gc, nb=ga*gb+gb*gd, nc=gc*ga+gd*gc, nd=gc*gb+gd*gd;
      ga=na;gb=nb;gc=nc;gd=nd;
    }
    // Y_g = combine gfin[0..g-1], tiled-8 pipelined spin loads
    float y1=0.f, y2=0.f;
    {
      const unsigned long long* Gp = gfin + (size_t)part*NG*P + p;
      for (int t0=0; t0<NG-1 && t0<g; t0+=8){
        unsigned long long v[8];
        #pragma unroll
        for (int j=0;j<8;j++){
          int jj = t0+j;
          v[j] = (jj < g) ? aload(Gp + (size_t)jj*P) : 0ULL;
        }
        #pragma unroll
        for (int j=0;j<8;j++){
          int jj = t0+j;
          if (jj < g){
            while (v[j]==SENT){ __builtin_amdgcn_s_sleep(2); v[j] = aload(Gp + (size_t)jj*P); }
          }
        }
        #pragma unroll
        for (int j=0;j<8;j++){
          int jj = t0+j;
          if (jj < g){
            union { unsigned long long u; float2 f; } w; w.u = v[j];
            float n1 = ga*y1 + gb*y2 + w.f.x;
            float n2 = gc*y1 + gd*y2 + w.f.y;
            y1=n1; y2=n2;
          }
        }
      }
    }
    // z = exclusive mate prefix (skip if computed in phase C)
    if (!have_z){
      for (int t0=0; t0<GS-1 && t0<iw; t0+=8){
        unsigned long long v[8];
        #pragma unroll
        for (int j=0;j<8;j++){
          int jj = t0+j;
          v[j] = (jj < iw) ? aload(Fp + (size_t)jj*P) : 0ULL;
        }
        #pragma unroll
        for (int j=0;j<8;j++){
          int jj = t0+j;
          if (jj < iw){
            while (v[j]==SENT){ __builtin_amdgcn_s_sleep(2); v[j] = aload(Fp + (size_t)jj*P); }
          }
        }
        #pragma unroll
        for (int j=0;j<8;j++){
          int jj = t0+j;
          if (jj < iw){
            union { unsigned long long u; float2 f; } w; w.u = v[j];
            float n1 = Ta*z1 + Tb*z2v + w.f.x;
            float n2 = Tc*z1 + Td*z2v + w.f.y;
            z1=n1; z2v=n2;
          }
        }
      }
    }
    float x1 = sa*y1 + sb*y2 + z1;
    float x2 = sc*y1 + sd*y2 + z2v;
    // in-LDS scan: overwrite sX column with bf16(x2)
    #pragma unroll
    for (int i=0;i<CL;i++){
      float u = bf2f(sX[i][part*256 + p]);
      float n1 = q.M11*x1 + q.M12*x2 + q.s1*u;
      float n2 = q.M21*x1 + q.M22*x2 + q.s2*u;
      x1 = n1; x2 = n2;
      sX[i][part*256 + p] = f2bf(x2);
    }
  }
  __syncthreads();

  // ---------------- out GEMM: 32 rows x 128 h ----------------------------------
  {
    int lane = tid & 63, w = tid >> 6;
    int ml = lane & 15, quad = lane >> 4;
    int mt = w & 1;
    int ntb = (w >> 1) * 2;
    f32x4 acc[2];
    acc[0] = (f32x4){0.f,0.f,0.f,0.f};
    acc[1] = (f32x4){0.f,0.f,0.f,0.f};
    for (int ks=0; ks<KDIM/32; ks++){
      short8 av = *(const short8*)&sX[mt*16 + ml][ks*32 + quad*8];
      #pragma unroll
      for (int j=0;j<2;j++){
        short8 bv = *(const short8*)(Bswz + ((size_t)(ks*4+quad)*H + (ntb+j)*16 + ml)*8);
        acc[j] = __builtin_amdgcn_mfma_f32_16x16x32_bf16(av, bv, acc[j], 0, 0, 0);
      }
    }
    #pragma unroll
    for (int j=0;j<2;j++){
      int h = (ntb+j)*16 + ml;
      float dv = Dv[h];
      #pragma unroll
      for (int r=0;r<4;r++){
        int l = c*CL + mt*16 + quad*4 + r;
        out[(size_t)l*H + h] = acc[j][r] + in[(size_t)l*H + h]*dv;
      }
    }
  }
}

extern "C" void kernel_launch(void* const* d_in, const int* in_sizes, int n_in,
                              void* d_out, int out_size, void* d_ws, size_t ws_size,
                              hipStream_t stream) {
  const float* in     = (const float*)d_in[0];   // (L,H)
  const float* A_diag = (const float*)d_in[1];   // (P,)
  const float* B      = (const float*)d_in[2];   // (P,H,2)
  const float* Cw     = (const float*)d_in[3];   // (H,P,2)
  const float* Dv     = (const float*)d_in[4];   // (H,)
  const float* steps  = (const float*)d_in[5];   // (P,)
  float* out = (float*)d_out;

  unsigned short* BWswz = (unsigned short*)d_ws;             // 128*512 bf16 (128KB)
  unsigned short* Bswz  = BWswz + (size_t)H*NBU;             // 512*128 bf16 (128KB)
  unsigned long long* finals = (unsigned long long*)(Bswz + (size_t)KDIM*H); // [2][NCH][P]
  unsigned long long* gfin   = finals + (size_t)2*NCH*P;     // [2][NG][P]

  prep_w<<<SENT_WORDS/512, 512, 0, stream>>>(B, Cw, BWswz, Bswz, finals);
  linoss_fused<<<NCH, 512, 0, stream>>>(in, A_diag, steps, Dv, BWswz, Bswz,
                                        finals, gfin, out);
}